// Round 5
// baseline (1198.426 us; speedup 1.0000x reference)
//
#include <hip/hip_runtime.h>
#include <cstdint>
#include <cstddef>

// Problem constants
#define B_N   16384
#define D_DIM 16
#define K_NBR 25
#define CAP   512       // per-row candidate buffer capacity
#define NSAMP 1024      // threshold sample count per row
#define MAXL  8         // CAP/64 local key slots per lane in select

// Workspace layout (memset zeroes only [0, WS_SQ_OFF)):
//   [0,256)       : float accum[2] {recon_sum, dot2_sum}
//   [256,+64K)    : u32  cnt[16384]
//   [+64K)        : float sq[16384]
//   [+64K)        : float T[16384]
//   [+16MB)       : u16  buf[16384*512]
#define WS_CNT_OFF  256
#define WS_SQ_OFF   (WS_CNT_OFF + 65536)
#define WS_T_OFF    (WS_SQ_OFF + 65536)
#define WS_BUF_OFF  (WS_T_OFF + 65536)

__device__ __forceinline__ float dot16(float4 a0, float4 a1, float4 a2, float4 a3,
                                       float4 b0, float4 b1, float4 b2, float4 b3) {
    float d = a0.x * b0.x;
    d = fmaf(a0.y, b0.y, d); d = fmaf(a0.z, b0.z, d); d = fmaf(a0.w, b0.w, d);
    d = fmaf(a1.x, b1.x, d); d = fmaf(a1.y, b1.y, d); d = fmaf(a1.z, b1.z, d); d = fmaf(a1.w, b1.w, d);
    d = fmaf(a2.x, b2.x, d); d = fmaf(a2.y, b2.y, d); d = fmaf(a2.z, b2.z, d); d = fmaf(a2.w, b2.w, d);
    d = fmaf(a3.x, b3.x, d); d = fmaf(a3.y, b3.y, d); d = fmaf(a3.z, b3.z, d); d = fmaf(a3.w, b3.w, d);
    return d;
}

__device__ __forceinline__ unsigned map_f32(float x) {
    unsigned u = __float_as_uint(x);
    return (u & 0x80000000u) ? ~u : (u | 0x80000000u);
}

// ---------------------------------------------------------------- prep: sq of raw rows + recon MSE
__global__ __launch_bounds__(256) void prep_kernel(const float4* __restrict__ rawv,
                                                   const float4* __restrict__ ov,
                                                   const float4* __restrict__ tv,
                                                   float* __restrict__ sq,
                                                   float* __restrict__ accum) {
    int i = blockIdx.x * 256 + threadIdx.x;
    float4 r0 = rawv[i*4+0], r1 = rawv[i*4+1], r2 = rawv[i*4+2], r3 = rawv[i*4+3];
    float s = r0.x*r0.x + r0.y*r0.y + r0.z*r0.z + r0.w*r0.w;
    s += r1.x*r1.x + r1.y*r1.y + r1.z*r1.z + r1.w*r1.w;
    s += r2.x*r2.x + r2.y*r2.y + r2.z*r2.z + r2.w*r2.w;
    s += r3.x*r3.x + r3.y*r3.y + r3.z*r3.z + r3.w*r3.w;
    sq[i] = s;

    float rs = 0.0f;
    #pragma unroll
    for (int q = 0; q < 4; ++q) {
        float4 o = ov[i*4+q], t = tv[i*4+q];
        float d;
        d = o.x - t.x; rs = fmaf(d, d, rs);
        d = o.y - t.y; rs = fmaf(d, d, rs);
        d = o.z - t.z; rs = fmaf(d, d, rs);
        d = o.w - t.w; rs = fmaf(d, d, rs);
    }
    #pragma unroll
    for (int off = 32; off >= 1; off >>= 1) rs += __shfl_down(rs, off, 64);
    if ((threadIdx.x & 63) == 0) atomicAdd(&accum[0], rs);
}

// ---------------------------------------------------------------- per-row distance threshold
// 16 threads/row, 64 samples each (j = t*256 + sidx*16 : 1024 multiples of 16).
// Each thread keeps its 3 smallest (shallow branchless chain); T[i] = exact
// 13th smallest of the 48 partials (>= true 13th of 1024 -> errs safe/larger).
__global__ __launch_bounds__(256) void thresh_kernel(const float4* __restrict__ rawv,
                                                     const float* __restrict__ sq,
                                                     float* __restrict__ T) {
    int rl   = threadIdx.x >> 4;     // row_local 0..15
    int sidx = threadIdx.x & 15;     // sample-slice 0..15
    int i = blockIdx.x * 16 + rl;

    float4 a0 = rawv[i*4+0], a1 = rawv[i*4+1], a2 = rawv[i*4+2], a3 = rawv[i*4+3];
    float sqi = sq[i];

    float s0 = 3e37f, s1 = 3e37f, s2 = 3e37f;   // ascending top-3
    #pragma unroll 4
    for (int t = 0; t < NSAMP / 16; ++t) {
        int j = t * 256 + sidx * 16;
        float4 b0 = rawv[j*4+0], b1 = rawv[j*4+1], b2 = rawv[j*4+2], b3 = rawv[j*4+3];
        float cur = sqi + sq[j] - 2.0f * dot16(a0,a1,a2,a3,b0,b1,b2,b3);
        float lo;
        lo = fminf(s0, cur); cur = fmaxf(s0, cur); s0 = lo;
        lo = fminf(s1, cur); cur = fmaxf(s1, cur); s1 = lo;
        lo = fminf(s2, cur); cur = fmaxf(s2, cur); s2 = lo;
    }

    __shared__ float V[16][48];
    V[rl][sidx*3+0] = s0; V[rl][sidx*3+1] = s1; V[rl][sidx*3+2] = s2;
    __syncthreads();

    // exact 13th smallest of the 48 via rank counting (unique value; ties benign)
    int cl0 = 0, cq0 = 0, cl1 = 0, cq1 = 0, cl2 = 0, cq2 = 0;
    for (int k = 0; k < 48; ++k) {
        float v = V[rl][k];
        cl0 += (v < s0); cq0 += (v <= s0);
        cl1 += (v < s1); cq1 += (v <= s1);
        cl2 += (v < s2); cq2 += (v <= s2);
    }
    if (cl0 <= 12 && 12 < cq0) T[i] = s0;
    else if (cl1 <= 12 && 12 < cq1) T[i] = s1;
    else if (cl2 <= 12 && 12 < cq2) T[i] = s2;
}

// ---------------------------------------------------------------- symmetric filter: j > i pairs only,
// append to both rows. d2 is bitwise-symmetric (fmaf chain and adds commute elementwise).
__global__ __launch_bounds__(256) void filter_kernel(const float4* __restrict__ rawv,
                                                     const float* __restrict__ sq,
                                                     const float* __restrict__ T,
                                                     unsigned* __restrict__ cnt,
                                                     unsigned short* __restrict__ buf) {
    int rg = blockIdx.x >> 5;        // 64 row groups of 256
    int s  = blockIdx.x & 31;        // 32 j-segments of 512
    if ((s << 9) + 511 <= (rg << 8)) return;   // no j > i in this tile
    int i  = (rg << 8) + threadIdx.x;

    float4 a0 = rawv[i*4+0], a1 = rawv[i*4+1], a2 = rawv[i*4+2], a3 = rawv[i*4+3];
    float sqi = sq[i];
    float Ti  = T[i];
    unsigned short* bpi = buf + (size_t)i * CAP;

    int j0 = s << 9, j1 = j0 + 512;
    for (int j = j0; j < j1; ++j) {
        float4 b0 = rawv[j*4+0], b1 = rawv[j*4+1], b2 = rawv[j*4+2], b3 = rawv[j*4+3];
        float sqj = sq[j];
        float Tj  = T[j];
        float d2 = sqi + sqj - 2.0f * dot16(a0,a1,a2,a3,b0,b1,b2,b3);
        bool upper = (j > i);
        if (upper && (d2 < Ti)) {
            unsigned old = atomicAdd(&cnt[i], 1u);
            if (old < CAP) bpi[old] = (unsigned short)j;
        }
        if (upper && (d2 < Tj)) {
            unsigned old = atomicAdd(&cnt[j], 1u);
            if (old < CAP) buf[(size_t)j * CAP + old] = (unsigned short)i;
        }
    }
}

// ---------------------------------------------------------------- select (bisection cutoff) + TSA point term
__global__ __launch_bounds__(256, 4) void select_point_kernel(const float4* __restrict__ latv,
                                                              const float4* __restrict__ rawv,
                                                              const float* __restrict__ sq,
                                                              const float* __restrict__ T,
                                                              const unsigned* __restrict__ cnt,
                                                              const unsigned short* __restrict__ buf,
                                                              float* __restrict__ accum) {
    int wave = threadIdx.x >> 6;
    int lane = threadIdx.x & 63;
    int pt   = blockIdx.x * 4 + wave;

    __shared__ int   nbrS[4][K_NBR];
    __shared__ float ZS[4][K_NBR * D_DIM];
    __shared__ float XS[4][K_NBR * D_DIM];
    __shared__ int   cntS[4];

    if (lane == 0) cntS[wave] = 0;

    // ---- phase A: recompute exact d2 for stored candidates (bit-identical to filter)
    float4 a0 = rawv[pt*4+0], a1 = rawv[pt*4+1], a2 = rawv[pt*4+2], a3 = rawv[pt*4+3];
    float sqi = sq[pt];
    unsigned craw = cnt[pt];
    int C = (int)(craw < CAP ? craw : CAP);
    const unsigned short* bp = buf + (size_t)pt * CAP;

    unsigned mkey[MAXL];   // keys only; j re-read from buf in phase C
    #pragma unroll
    for (int t = 0; t < MAXL; ++t) {
        int c = t * 64 + lane;
        unsigned key = 0xFFFFFFFFu;
        if (c < C) {
            int j = (int)bp[c];
            float4 b0 = rawv[j*4+0], b1 = rawv[j*4+1], b2 = rawv[j*4+2], b3 = rawv[j*4+3];
            float d2 = sqi + sq[j] - 2.0f * dot16(a0,a1,a2,a3,b0,b1,b2,b3);
            key = map_f32(d2);
        }
        mkey[t] = key;
    }

    // ---- phase B: bisection for T25 = smallest key with count(<=key) >= 25
    unsigned lo = 0x80000000u;          // map(0.0f); d2 >= 0
    unsigned hi = map_f32(T[pt]);       // all stored keys < this
    for (int it = 0; it < 32 && lo < hi; ++it) {
        unsigned mid = lo + ((hi - lo) >> 1);
        unsigned c25 = 0;
        #pragma unroll
        for (int t = 0; t < MAXL; ++t)
            c25 += (unsigned)__builtin_popcountll(__ballot(mkey[t] <= mid));
        if (c25 >= K_NBR) hi = mid; else lo = mid + 1;
    }
    unsigned T25 = hi;

    __syncthreads();   // cntS zero visible before atomics

    // ---- phase C: collect neighbor set (unordered; set semantics suffice)
    #pragma unroll
    for (int t = 0; t < MAXL; ++t) {
        int c = t * 64 + lane;
        if (mkey[t] <= T25) {
            int pos = atomicAdd(&cntS[wave], 1);
            if (pos < K_NBR) nbrS[wave][pos] = (int)bp[c];
        }
    }
    __syncthreads();
    if (lane == 0) {
        int got = cntS[wave]; got = got < K_NBR ? got : K_NBR;
        if (got < K_NBR) {          // rare; bounded impact
            int pad = (got > 0) ? nbrS[wave][0] : pt;
            for (int r = got; r < K_NBR; ++r) nbrS[wave][r] = pad;
        }
    }
    __syncthreads();

    // ---- gather neighbor rows (latent -> Z, raw -> X)
    if (lane < K_NBR) {
        int n = nbrS[wave][lane];
        float4* z = (float4*)&ZS[wave][lane * D_DIM];
        float4* x = (float4*)&XS[wave][lane * D_DIM];
        z[0] = latv[n*4+0]; z[1] = latv[n*4+1]; z[2] = latv[n*4+2]; z[3] = latv[n*4+3];
        x[0] = rawv[n*4+0]; x[1] = rawv[n*4+1]; x[2] = rawv[n*4+2]; x[3] = rawv[n*4+3];
    }
    __syncthreads();

    // ---- eig phase: 4 groups of 16 lanes: (Z,X) x (half0, half1)
    int a    = lane & 15;            // row/col index
    int com  = lane & 16;            // 0 -> Z (latent), 16 -> X (raw)
    int hb   = lane >> 5;            // work-half
    int sbase = lane & 48;           // shuffle base of this 16-lane group
    float* M = com ? &XS[wave][0] : &ZS[wave][0];

    // center column a; k-range split between halves
    int k0 = hb ? 13 : 0;
    int k1 = hb ? 25 : 13;
    {
        float s = 0.0f;
        for (int k = k0; k < k1; ++k) s += M[k * D_DIM + a];
        s += __shfl_xor(s, 32, 64);
        float mean = s * 0.04f;       // 1/25
        for (int k = k0; k < k1; ++k) M[k * D_DIM + a] -= mean;
    }
    __syncthreads();

    // covariance row a, k-split + combine (global scale irrelevant for eigvecs)
    float row[16];
    #pragma unroll
    for (int b = 0; b < 16; ++b) row[b] = 0.0f;
    for (int k = k0; k < k1; ++k) {
        float va = M[k * D_DIM + a];
        #pragma unroll
        for (int b = 0; b < 16; ++b) row[b] = fmaf(va, M[k * D_DIM + b], row[b]);
    }
    #pragma unroll
    for (int b = 0; b < 16; ++b) row[b] += __shfl_xor(row[b], 32, 64);

    // normalize by max-abs
    float mm = 1e-30f;
    #pragma unroll
    for (int b = 0; b < 16; ++b) mm = fmaxf(mm, fabsf(row[b]));
    #pragma unroll
    for (int off = 1; off < 16; off <<= 1) mm = fmaxf(mm, __shfl_xor(mm, off, 64));
    float inv = 1.0f / mm;
    #pragma unroll
    for (int b = 0; b < 16; ++b) row[b] *= inv;

    int bbase = sbase + (hb << 3);   // shuffle src base for this half's b-range

    // 3 squarings, b-half split: net C^8
    for (int sq3 = 0; sq3 < 3; ++sq3) {
        float rh[8];
        #pragma unroll
        for (int bi = 0; bi < 8; ++bi) rh[bi] = hb ? row[8 + bi] : row[bi];
        float nr[16];
        #pragma unroll
        for (int c = 0; c < 16; ++c) nr[c] = 0.0f;
        #pragma unroll
        for (int bi = 0; bi < 8; ++bi) {
            float coef = rh[bi];
            #pragma unroll
            for (int c = 0; c < 16; ++c)
                nr[c] = fmaf(coef, __shfl(row[c], bbase + bi, 64), nr[c]);
        }
        #pragma unroll
        for (int c = 0; c < 16; ++c) nr[c] += __shfl_xor(nr[c], 32, 64);
        mm = 1e-30f;
        #pragma unroll
        for (int c = 0; c < 16; ++c) mm = fmaxf(mm, fabsf(nr[c]));
        #pragma unroll
        for (int off = 1; off < 16; off <<= 1) mm = fmaxf(mm, __shfl_xor(mm, off, 64));
        inv = 1.0f / mm;
        #pragma unroll
        for (int c = 0; c < 16; ++c) row[c] = nr[c] * inv;
    }

    // 16 power iterations on C^8, b-half split: effective ~C^128
    float rh[8];
    #pragma unroll
    for (int bi = 0; bi < 8; ++bi) rh[bi] = hb ? row[8 + bi] : row[bi];
    float v = 1.0f + 0.0625f * (float)a;
    for (int it = 0; it < 16; ++it) {
        float w = 0.0f;
        #pragma unroll
        for (int bi = 0; bi < 8; ++bi)
            w = fmaf(rh[bi], __shfl(v, bbase + bi, 64), w);
        w += __shfl_xor(w, 32, 64);
        float n2 = w * w;
        #pragma unroll
        for (int off = 1; off < 16; off <<= 1) n2 += __shfl_xor(n2, off, 64);
        v = w * rsqrtf(n2 + 1e-37f);
    }
    {
        float n2 = v * v;
        #pragma unroll
        for (int off = 1; off < 16; off <<= 1) n2 += __shfl_xor(n2, off, 64);
        v = v / sqrtf(n2 + 1e-37f);
    }

    // cross-community dot: lanes 0..15 hold u (Z), 16..31 hold v (X)
    float p = v * __shfl_xor(v, 16, 64);
    #pragma unroll
    for (int off = 1; off < 16; off <<= 1) p += __shfl_xor(p, off, 64);
    if (lane == 0) atomicAdd(&accum[1], p * p);
}

// ---------------------------------------------------------------- combine
__global__ void final_kernel(const float* __restrict__ accum, float* __restrict__ out) {
    float recon = accum[0] * (1.0f / (float)(B_N * D_DIM));
    float tsa   = 2.0f - 2.0f * (accum[1] * (1.0f / (float)B_N));
    out[0] = recon + 0.1f * tsa;
}

extern "C" void kernel_launch(void* const* d_in, const int* in_sizes, int n_in,
                              void* d_out, int out_size, void* d_ws, size_t ws_size,
                              hipStream_t stream) {
    const float* outputs = (const float*)d_in[0];
    const float* targets = (const float*)d_in[1];
    const float* latent  = (const float*)d_in[2];
    const float* raw     = (const float*)d_in[3];

    float* accum        = (float*)d_ws;
    unsigned* cnt       = (unsigned*)((char*)d_ws + WS_CNT_OFF);
    float* sq           = (float*)((char*)d_ws + WS_SQ_OFF);
    float* T            = (float*)((char*)d_ws + WS_T_OFF);
    unsigned short* buf = (unsigned short*)((char*)d_ws + WS_BUF_OFF);

    const float4* rawv = (const float4*)raw;
    const float4* latv = (const float4*)latent;

    hipMemsetAsync(d_ws, 0, WS_SQ_OFF, stream);  // zero accum + cnt
    prep_kernel<<<B_N / 256, 256, 0, stream>>>(rawv, (const float4*)outputs,
                                               (const float4*)targets, sq, accum);
    thresh_kernel<<<B_N / 16, 256, 0, stream>>>(rawv, sq, T);
    filter_kernel<<<(B_N / 256) * 32, 256, 0, stream>>>(rawv, sq, T, cnt, buf);
    select_point_kernel<<<B_N / 4, 256, 0, stream>>>(latv, rawv, sq, T, cnt, buf, accum);
    final_kernel<<<1, 1, 0, stream>>>(accum, (float*)d_out);
}

// Round 6
// 682.535 us; speedup vs baseline: 1.7558x; 1.7558x over previous
//
#include <hip/hip_runtime.h>
#include <cstdint>
#include <cstddef>

// Problem constants
#define B_N   16384
#define D_DIM 16
#define K_NBR 25
#define CAP   384       // per-row LDS candidate capacity (E[C]~230, sigma~60)
#define MAXL  6         // CAP/64
#define NSAMP 1024      // threshold sample count per row

// Workspace: accum 256B | sq 64KB | T 64KB | rawh 512KB | rawl 512KB
#define WS_SQ_OFF   256
#define WS_T_OFF    (WS_SQ_OFF + 65536)
#define WS_RAWH_OFF (WS_T_OFF + 65536)
#define WS_RAWL_OFF (WS_RAWH_OFF + B_N * D_DIM * 2)

typedef __attribute__((ext_vector_type(8))) short bf16x8;
typedef __attribute__((ext_vector_type(4))) float f32x4;

__device__ __forceinline__ float dot16(float4 a0, float4 a1, float4 a2, float4 a3,
                                       float4 b0, float4 b1, float4 b2, float4 b3) {
    float d = a0.x * b0.x;
    d = fmaf(a0.y, b0.y, d); d = fmaf(a0.z, b0.z, d); d = fmaf(a0.w, b0.w, d);
    d = fmaf(a1.x, b1.x, d); d = fmaf(a1.y, b1.y, d); d = fmaf(a1.z, b1.z, d); d = fmaf(a1.w, b1.w, d);
    d = fmaf(a2.x, b2.x, d); d = fmaf(a2.y, b2.y, d); d = fmaf(a2.z, b2.z, d); d = fmaf(a2.w, b2.w, d);
    d = fmaf(a3.x, b3.x, d); d = fmaf(a3.y, b3.y, d); d = fmaf(a3.z, b3.z, d); d = fmaf(a3.w, b3.w, d);
    return d;
}

__device__ __forceinline__ unsigned map_f32(float x) {
    unsigned u = __float_as_uint(x);
    return (u & 0x80000000u) ? ~u : (u | 0x80000000u); // order-preserving
}

__device__ __forceinline__ unsigned short f2bf(float x) {   // RNE f32->bf16 bits
    unsigned u = __float_as_uint(x);
    unsigned r = (u + 0x7FFFu + ((u >> 16) & 1u)) >> 16;
    return (unsigned short)r;
}
__device__ __forceinline__ float bf2f(unsigned short h) {
    return __uint_as_float(((unsigned)h) << 16);
}

// ---------------------------------------------------------------- prep: sq + recon MSE + bf16 hi/lo split
__global__ __launch_bounds__(256) void prep_kernel(const float4* __restrict__ rawv,
                                                   const float4* __restrict__ ov,
                                                   const float4* __restrict__ tv,
                                                   float* __restrict__ sq,
                                                   unsigned short* __restrict__ rawh,
                                                   unsigned short* __restrict__ rawl,
                                                   float* __restrict__ accum) {
    int i = blockIdx.x * 256 + threadIdx.x;
    float v[16];
    {
        float4 r0 = rawv[i*4+0], r1 = rawv[i*4+1], r2 = rawv[i*4+2], r3 = rawv[i*4+3];
        v[0]=r0.x; v[1]=r0.y; v[2]=r0.z; v[3]=r0.w;
        v[4]=r1.x; v[5]=r1.y; v[6]=r1.z; v[7]=r1.w;
        v[8]=r2.x; v[9]=r2.y; v[10]=r2.z; v[11]=r2.w;
        v[12]=r3.x; v[13]=r3.y; v[14]=r3.z; v[15]=r3.w;
    }
    float s = 0.0f;
    unsigned short h[16], l[16];
    #pragma unroll
    for (int k = 0; k < 16; ++k) {
        s = fmaf(v[k], v[k], s);
        unsigned short hh = f2bf(v[k]);
        h[k] = hh;
        l[k] = f2bf(v[k] - bf2f(hh));
    }
    sq[i] = s;
    #pragma unroll
    for (int q = 0; q < 4; ++q) {
        ((ushort4*)(rawh + (size_t)i*16))[q] = make_ushort4(h[q*4], h[q*4+1], h[q*4+2], h[q*4+3]);
        ((ushort4*)(rawl + (size_t)i*16))[q] = make_ushort4(l[q*4], l[q*4+1], l[q*4+2], l[q*4+3]);
    }

    float rs = 0.0f;
    #pragma unroll
    for (int q = 0; q < 4; ++q) {
        float4 o = ov[i*4+q], t = tv[i*4+q];
        float d;
        d = o.x - t.x; rs = fmaf(d, d, rs);
        d = o.y - t.y; rs = fmaf(d, d, rs);
        d = o.z - t.z; rs = fmaf(d, d, rs);
        d = o.w - t.w; rs = fmaf(d, d, rs);
    }
    #pragma unroll
    for (int off = 32; off >= 1; off >>= 1) rs += __shfl_down(rs, off, 64);
    if ((threadIdx.x & 63) == 0) atomicAdd(&accum[0], rs);
}

// ---------------------------------------------------------------- per-row distance threshold (R5 structure)
// 16 threads/row x 64 samples; top-3 each; T[i] = exact 13th of the 48 partials (errs large = safe).
__global__ __launch_bounds__(256) void thresh_kernel(const float4* __restrict__ rawv,
                                                     const float* __restrict__ sq,
                                                     float* __restrict__ T) {
    int rl   = threadIdx.x >> 4;
    int sidx = threadIdx.x & 15;
    int i = blockIdx.x * 16 + rl;

    float4 a0 = rawv[i*4+0], a1 = rawv[i*4+1], a2 = rawv[i*4+2], a3 = rawv[i*4+3];
    float sqi = sq[i];

    float s0 = 3e37f, s1 = 3e37f, s2 = 3e37f;
    #pragma unroll 4
    for (int t = 0; t < NSAMP / 16; ++t) {
        int j = t * 256 + sidx * 16;
        float4 b0 = rawv[j*4+0], b1 = rawv[j*4+1], b2 = rawv[j*4+2], b3 = rawv[j*4+3];
        float cur = sqi + sq[j] - 2.0f * dot16(a0,a1,a2,a3,b0,b1,b2,b3);
        float lo;
        lo = fminf(s0, cur); cur = fmaxf(s0, cur); s0 = lo;
        lo = fminf(s1, cur); cur = fmaxf(s1, cur); s1 = lo;
        lo = fminf(s2, cur); cur = fmaxf(s2, cur); s2 = lo;
    }

    __shared__ float V[16][48];
    V[rl][sidx*3+0] = s0; V[rl][sidx*3+1] = s1; V[rl][sidx*3+2] = s2;
    __syncthreads();

    int cl0 = 0, cq0 = 0, cl1 = 0, cq1 = 0, cl2 = 0, cq2 = 0;
    for (int k = 0; k < 48; ++k) {
        float v = V[rl][k];
        cl0 += (v < s0); cq0 += (v <= s0);
        cl1 += (v < s1); cq1 += (v <= s1);
        cl2 += (v < s2); cq2 += (v <= s2);
    }
    if (cl0 <= 12 && 12 < cq0) T[i] = s0;
    else if (cl1 <= 12 && 12 < cq1) T[i] = s1;
    else if (cl2 <= 12 && 12 < cq2) T[i] = s2;
}

// ---------------------------------------------------------------- fused MFMA scan + select + eig + dot
// Block = 16 i-rows; 4 waves stride 1024 j-tiles with mfma_f32_16x16x32_bf16.
// A-frag = [ah|al] along K; B-frags [bh|bh], [bl|bl] -> acc = a.(bh+bl) ~ a.b (err ~2^-17).
// Candidates (d2 < T) -> LDS lists as (key16<<16)|j; per-row wave bisection -> top-25; verified eig.
__global__ __launch_bounds__(256) void tsa_kernel(const unsigned short* __restrict__ rawh,
                                                  const unsigned short* __restrict__ rawl,
                                                  const float4* __restrict__ latv,
                                                  const float4* __restrict__ rawv,
                                                  const float* __restrict__ sq,
                                                  const float* __restrict__ T,
                                                  float* __restrict__ accum) {
    __shared__ unsigned keyS[16 * CAP];       // 24 KB
    __shared__ int      cntS[16];
    __shared__ float    ZS[4][K_NBR * D_DIM]; // 6.25 KB
    __shared__ float    XS[4][K_NBR * D_DIM]; // 6.25 KB
    __shared__ int      nbrS[4][K_NBR];
    __shared__ int      scntS[4];

    int tid  = threadIdx.x;
    int wave = tid >> 6;
    int lane = tid & 63;
    int quad = lane >> 4;
    int lnib = lane & 15;
    int i0   = blockIdx.x * 16;

    if (tid < 16) cntS[tid] = 0;

    // A-frag: 16x16x32 layout A[m=lane&15][k=quad*8+jj]; pack k<16 = ah, k>=16 = al
    const unsigned short* abase = (quad < 2 ? rawh : rawl) + (size_t)(i0 + lnib) * 16 + (quad & 1) * 8;
    bf16x8 afrag = *(const bf16x8*)abase;

    float sqi[4], Ti[4];
    #pragma unroll
    for (int r = 0; r < 4; ++r) { int m = quad * 4 + r; sqi[r] = sq[i0 + m]; Ti[r] = T[i0 + m]; }

    __syncthreads();

    // ---- phase 1: MFMA distance scan over all j-tiles
    for (int t = wave; t < B_N / 16; t += 4) {
        int j0 = t * 16;
        int j  = j0 + lnib;
        bf16x8 bh = *(const bf16x8*)(rawh + (size_t)j * 16 + (quad & 1) * 8); // [bh|bh]
        bf16x8 bl = *(const bf16x8*)(rawl + (size_t)j * 16 + (quad & 1) * 8); // [bl|bl]
        float sqj = sq[j];
        f32x4 acc = {0.f, 0.f, 0.f, 0.f};
        acc = __builtin_amdgcn_mfma_f32_16x16x32_bf16(afrag, bl, acc, 0, 0, 0);
        acc = __builtin_amdgcn_mfma_f32_16x16x32_bf16(afrag, bh, acc, 0, 0, 0);
        // C/D layout: col=lane&15 (j), row=quad*4+reg (i)
        #pragma unroll
        for (int r = 0; r < 4; ++r) {
            float d2 = sqi[r] + sqj - 2.0f * acc[r];
            int m = quad * 4 + r;
            bool cond = (d2 < Ti[r]) && (j != i0 + m);
            if (cond) {
                int pos = atomicAdd(&cntS[m], 1);
                if (pos < CAP)
                    keyS[m * CAP + pos] = (map_f32(d2) & 0xFFFF0000u) | (unsigned)j;
            }
        }
    }
    __syncthreads();

    // ---- phases 2+3: per wave, 4 rows sequentially (uniform barriers)
    for (int rr = 0; rr < 4; ++rr) {
        int m  = wave * 4 + rr;
        int pt = i0 + m;
        int C = cntS[m]; C = C < CAP ? C : CAP;

        unsigned kl[MAXL];
        #pragma unroll
        for (int tt = 0; tt < MAXL; ++tt) {
            int c = tt * 64 + lane;
            kl[tt] = (c < C) ? keyS[m * CAP + c] : 0xFFFFFFFFu;
        }
        // bisection: smallest T25 with count(<= T25) >= 25 (keys unique via j low bits)
        unsigned lo = 0, hi = 0xFFFFFFFEu;
        for (int it = 0; it < 32 && lo < hi; ++it) {
            unsigned mid = lo + ((hi - lo) >> 1);
            unsigned cc = 0;
            #pragma unroll
            for (int tt = 0; tt < MAXL; ++tt)
                cc += (unsigned)__builtin_popcountll(__ballot(kl[tt] <= mid));
            if (cc >= K_NBR) hi = mid; else lo = mid + 1;
        }
        unsigned T25 = hi;

        if (lane == 0) scntS[wave] = 0;
        __syncthreads();
        #pragma unroll
        for (int tt = 0; tt < MAXL; ++tt) {
            if (kl[tt] <= T25) {
                int pos = atomicAdd(&scntS[wave], 1);
                if (pos < K_NBR) nbrS[wave][pos] = (int)(kl[tt] & 0xFFFFu);
            }
        }
        __syncthreads();
        if (lane == 0) {
            int got = scntS[wave]; got = got < K_NBR ? got : K_NBR;
            if (got < K_NBR) {   // essentially impossible; bounded impact
                int pad = (got > 0) ? nbrS[wave][0] : pt;
                for (int q = got; q < K_NBR; ++q) nbrS[wave][q] = pad;
            }
        }
        __syncthreads();

        // gather neighbor rows (latent -> Z, raw -> X)
        if (lane < K_NBR) {
            int n = nbrS[wave][lane];
            float4* z = (float4*)&ZS[wave][lane * D_DIM];
            float4* x = (float4*)&XS[wave][lane * D_DIM];
            z[0] = latv[n*4+0]; z[1] = latv[n*4+1]; z[2] = latv[n*4+2]; z[3] = latv[n*4+3];
            x[0] = rawv[n*4+0]; x[1] = rawv[n*4+1]; x[2] = rawv[n*4+2]; x[3] = rawv[n*4+3];
        }
        __syncthreads();

        // eig phase (verified): 4 groups of 16 lanes: (Z,X) x (half0, half1)
        int a     = lane & 15;
        int com   = lane & 16;
        int hb    = lane >> 5;
        int sbase = lane & 48;
        float* M = com ? &XS[wave][0] : &ZS[wave][0];

        int k0 = hb ? 13 : 0;
        int k1 = hb ? 25 : 13;
        {
            float s = 0.0f;
            for (int k = k0; k < k1; ++k) s += M[k * D_DIM + a];
            s += __shfl_xor(s, 32, 64);
            float mean = s * 0.04f;
            for (int k = k0; k < k1; ++k) M[k * D_DIM + a] -= mean;
        }
        __syncthreads();

        float row[16];
        #pragma unroll
        for (int b = 0; b < 16; ++b) row[b] = 0.0f;
        for (int k = k0; k < k1; ++k) {
            float va = M[k * D_DIM + a];
            #pragma unroll
            for (int b = 0; b < 16; ++b) row[b] = fmaf(va, M[k * D_DIM + b], row[b]);
        }
        #pragma unroll
        for (int b = 0; b < 16; ++b) row[b] += __shfl_xor(row[b], 32, 64);

        float mm = 1e-30f;
        #pragma unroll
        for (int b = 0; b < 16; ++b) mm = fmaxf(mm, fabsf(row[b]));
        #pragma unroll
        for (int off = 1; off < 16; off <<= 1) mm = fmaxf(mm, __shfl_xor(mm, off, 64));
        float inv = 1.0f / mm;
        #pragma unroll
        for (int b = 0; b < 16; ++b) row[b] *= inv;

        int bbase = sbase + (hb << 3);

        for (int sq3 = 0; sq3 < 3; ++sq3) {   // net C^8
            float rh[8];
            #pragma unroll
            for (int bi = 0; bi < 8; ++bi) rh[bi] = hb ? row[8 + bi] : row[bi];
            float nr[16];
            #pragma unroll
            for (int c = 0; c < 16; ++c) nr[c] = 0.0f;
            #pragma unroll
            for (int bi = 0; bi < 8; ++bi) {
                float coef = rh[bi];
                #pragma unroll
                for (int c = 0; c < 16; ++c)
                    nr[c] = fmaf(coef, __shfl(row[c], bbase + bi, 64), nr[c]);
            }
            #pragma unroll
            for (int c = 0; c < 16; ++c) nr[c] += __shfl_xor(nr[c], 32, 64);
            mm = 1e-30f;
            #pragma unroll
            for (int c = 0; c < 16; ++c) mm = fmaxf(mm, fabsf(nr[c]));
            #pragma unroll
            for (int off = 1; off < 16; off <<= 1) mm = fmaxf(mm, __shfl_xor(mm, off, 64));
            inv = 1.0f / mm;
            #pragma unroll
            for (int c = 0; c < 16; ++c) row[c] = nr[c] * inv;
        }

        float rh[8];
        #pragma unroll
        for (int bi = 0; bi < 8; ++bi) rh[bi] = hb ? row[8 + bi] : row[bi];
        float v = 1.0f + 0.0625f * (float)a;
        for (int it = 0; it < 16; ++it) {     // ~C^128 effective
            float w = 0.0f;
            #pragma unroll
            for (int bi = 0; bi < 8; ++bi)
                w = fmaf(rh[bi], __shfl(v, bbase + bi, 64), w);
            w += __shfl_xor(w, 32, 64);
            float n2 = w * w;
            #pragma unroll
            for (int off = 1; off < 16; off <<= 1) n2 += __shfl_xor(n2, off, 64);
            v = w * rsqrtf(n2 + 1e-37f);
        }
        {
            float n2 = v * v;
            #pragma unroll
            for (int off = 1; off < 16; off <<= 1) n2 += __shfl_xor(n2, off, 64);
            v = v / sqrtf(n2 + 1e-37f);
        }

        float p = v * __shfl_xor(v, 16, 64);
        #pragma unroll
        for (int off = 1; off < 16; off <<= 1) p += __shfl_xor(p, off, 64);
        if (lane == 0) atomicAdd(&accum[1], p * p);
        __syncthreads();
    }
}

// ---------------------------------------------------------------- combine
__global__ void final_kernel(const float* __restrict__ accum, float* __restrict__ out) {
    float recon = accum[0] * (1.0f / (float)(B_N * D_DIM));
    float tsa   = 2.0f - 2.0f * (accum[1] * (1.0f / (float)B_N));
    out[0] = recon + 0.1f * tsa;
}

extern "C" void kernel_launch(void* const* d_in, const int* in_sizes, int n_in,
                              void* d_out, int out_size, void* d_ws, size_t ws_size,
                              hipStream_t stream) {
    const float* outputs = (const float*)d_in[0];
    const float* targets = (const float*)d_in[1];
    const float* latent  = (const float*)d_in[2];
    const float* raw     = (const float*)d_in[3];

    float* accum         = (float*)d_ws;
    float* sq            = (float*)((char*)d_ws + WS_SQ_OFF);
    float* T             = (float*)((char*)d_ws + WS_T_OFF);
    unsigned short* rawh = (unsigned short*)((char*)d_ws + WS_RAWH_OFF);
    unsigned short* rawl = (unsigned short*)((char*)d_ws + WS_RAWL_OFF);

    const float4* rawv = (const float4*)raw;
    const float4* latv = (const float4*)latent;

    hipMemsetAsync(d_ws, 0, 256, stream);  // zero accum
    prep_kernel<<<B_N / 256, 256, 0, stream>>>(rawv, (const float4*)outputs,
                                               (const float4*)targets, sq, rawh, rawl, accum);
    thresh_kernel<<<B_N / 16, 256, 0, stream>>>(rawv, sq, T);
    tsa_kernel<<<B_N / 16, 256, 0, stream>>>(rawh, rawl, latv, rawv, sq, T, accum);
    final_kernel<<<1, 1, 0, stream>>>(accum, (float*)d_out);
}

// Round 7
// 475.882 us; speedup vs baseline: 2.5183x; 1.4343x over previous
//
#include <hip/hip_runtime.h>
#include <cstdint>
#include <cstddef>

// Problem constants
#define B_N   16384
#define D_DIM 16
#define K_NBR 25
#define CAP   384       // per-row LDS candidate capacity (E[C]~208, sigma~57)
#define MAXL  6         // CAP/64
#define NSAMP 1024      // threshold sample count per row

// Workspace: accum 256B | sq 64KB | T 64KB | rawh 512KB | rawl 512KB
#define WS_SQ_OFF   256
#define WS_T_OFF    (WS_SQ_OFF + 65536)
#define WS_RAWH_OFF (WS_T_OFF + 65536)
#define WS_RAWL_OFF (WS_RAWH_OFF + B_N * D_DIM * 2)

typedef __attribute__((ext_vector_type(8))) short bf16x8;
typedef __attribute__((ext_vector_type(4))) float f32x4;

__device__ __forceinline__ unsigned map_f32(float x) {
    unsigned u = __float_as_uint(x);
    return (u & 0x80000000u) ? ~u : (u | 0x80000000u); // order-preserving
}

__device__ __forceinline__ unsigned short f2bf(float x) {   // RNE f32->bf16 bits
    unsigned u = __float_as_uint(x);
    unsigned r = (u + 0x7FFFu + ((u >> 16) & 1u)) >> 16;
    return (unsigned short)r;
}
__device__ __forceinline__ float bf2f(unsigned short h) {
    return __uint_as_float(((unsigned)h) << 16);
}

// ---------------------------------------------------------------- prep: sq + recon MSE + bf16 hi/lo split
__global__ __launch_bounds__(256) void prep_kernel(const float4* __restrict__ rawv,
                                                   const float4* __restrict__ ov,
                                                   const float4* __restrict__ tv,
                                                   float* __restrict__ sq,
                                                   unsigned short* __restrict__ rawh,
                                                   unsigned short* __restrict__ rawl,
                                                   float* __restrict__ accum) {
    int i = blockIdx.x * 256 + threadIdx.x;
    float v[16];
    {
        float4 r0 = rawv[i*4+0], r1 = rawv[i*4+1], r2 = rawv[i*4+2], r3 = rawv[i*4+3];
        v[0]=r0.x; v[1]=r0.y; v[2]=r0.z; v[3]=r0.w;
        v[4]=r1.x; v[5]=r1.y; v[6]=r1.z; v[7]=r1.w;
        v[8]=r2.x; v[9]=r2.y; v[10]=r2.z; v[11]=r2.w;
        v[12]=r3.x; v[13]=r3.y; v[14]=r3.z; v[15]=r3.w;
    }
    float s = 0.0f;
    unsigned short h[16], l[16];
    #pragma unroll
    for (int k = 0; k < 16; ++k) {
        s = fmaf(v[k], v[k], s);
        unsigned short hh = f2bf(v[k]);
        h[k] = hh;
        l[k] = f2bf(v[k] - bf2f(hh));
    }
    sq[i] = s;
    #pragma unroll
    for (int q = 0; q < 4; ++q) {
        ((ushort4*)(rawh + (size_t)i*16))[q] = make_ushort4(h[q*4], h[q*4+1], h[q*4+2], h[q*4+3]);
        ((ushort4*)(rawl + (size_t)i*16))[q] = make_ushort4(l[q*4], l[q*4+1], l[q*4+2], l[q*4+3]);
    }

    float rs = 0.0f;
    #pragma unroll
    for (int q = 0; q < 4; ++q) {
        float4 o = ov[i*4+q], t = tv[i*4+q];
        float d;
        d = o.x - t.x; rs = fmaf(d, d, rs);
        d = o.y - t.y; rs = fmaf(d, d, rs);
        d = o.z - t.z; rs = fmaf(d, d, rs);
        d = o.w - t.w; rs = fmaf(d, d, rs);
    }
    #pragma unroll
    for (int off = 32; off >= 1; off >>= 1) rs += __shfl_down(rs, off, 64);
    if ((threadIdx.x & 63) == 0) atomicAdd(&accum[0], rs);
}

// ---------------------------------------------------------------- per-row distance threshold, LDS-staged
// Stage the shared 1024 sample rows (bf16-hi) + their sq once per block; 16 threads/row x 64
// samples each; top-3 chains; T[i] = exact 13th of 48 partials + margin (errs large = safe).
__global__ __launch_bounds__(256) void thresh_kernel(const float4* __restrict__ rawv,
                                                     const unsigned short* __restrict__ rawh,
                                                     const float* __restrict__ sq,
                                                     float* __restrict__ T) {
    __shared__ unsigned short sampH[NSAMP * 16];  // 32 KB
    __shared__ float sampSq[NSAMP];               // 4 KB
    __shared__ float V[16][48];                   // 3 KB

    int tid = threadIdx.x;
    for (int s = tid; s < NSAMP; s += 256) {
        int js = s << 4;
        const uint4* src = (const uint4*)(rawh + (size_t)js * 16);
        ((uint4*)(sampH + s * 16))[0] = src[0];
        ((uint4*)(sampH + s * 16))[1] = src[1];
        sampSq[s] = sq[js];
    }

    int rl   = tid >> 4;
    int sidx = tid & 15;
    int i = blockIdx.x * 16 + rl;

    float a[16];
    {
        float4 r0 = rawv[i*4+0], r1 = rawv[i*4+1], r2 = rawv[i*4+2], r3 = rawv[i*4+3];
        a[0]=r0.x; a[1]=r0.y; a[2]=r0.z; a[3]=r0.w;
        a[4]=r1.x; a[5]=r1.y; a[6]=r1.z; a[7]=r1.w;
        a[8]=r2.x; a[9]=r2.y; a[10]=r2.z; a[11]=r2.w;
        a[12]=r3.x; a[13]=r3.y; a[14]=r3.z; a[15]=r3.w;
    }
    float sqi = sq[i];
    __syncthreads();

    float s0 = 3e37f, s1 = 3e37f, s2 = 3e37f;
    for (int t = 0; t < NSAMP / 16; ++t) {
        int s = t * 16 + sidx;      // interleaved: consecutive lanes -> consecutive rows
        const uint4* bp = (const uint4*)(sampH + s * 16);
        uint4 h0 = bp[0], h1 = bp[1];
        float dot = 0.0f;
        unsigned w;
        w = h0.x; dot = fmaf(a[0],  __uint_as_float(w << 16), dot); dot = fmaf(a[1],  __uint_as_float(w & 0xFFFF0000u), dot);
        w = h0.y; dot = fmaf(a[2],  __uint_as_float(w << 16), dot); dot = fmaf(a[3],  __uint_as_float(w & 0xFFFF0000u), dot);
        w = h0.z; dot = fmaf(a[4],  __uint_as_float(w << 16), dot); dot = fmaf(a[5],  __uint_as_float(w & 0xFFFF0000u), dot);
        w = h0.w; dot = fmaf(a[6],  __uint_as_float(w << 16), dot); dot = fmaf(a[7],  __uint_as_float(w & 0xFFFF0000u), dot);
        w = h1.x; dot = fmaf(a[8],  __uint_as_float(w << 16), dot); dot = fmaf(a[9],  __uint_as_float(w & 0xFFFF0000u), dot);
        w = h1.y; dot = fmaf(a[10], __uint_as_float(w << 16), dot); dot = fmaf(a[11], __uint_as_float(w & 0xFFFF0000u), dot);
        w = h1.z; dot = fmaf(a[12], __uint_as_float(w << 16), dot); dot = fmaf(a[13], __uint_as_float(w & 0xFFFF0000u), dot);
        w = h1.w; dot = fmaf(a[14], __uint_as_float(w << 16), dot); dot = fmaf(a[15], __uint_as_float(w & 0xFFFF0000u), dot);
        float cur = sqi + sampSq[s] - 2.0f * dot;
        float lo;
        lo = fminf(s0, cur); cur = fmaxf(s0, cur); s0 = lo;
        lo = fminf(s1, cur); cur = fmaxf(s1, cur); s1 = lo;
        lo = fminf(s2, cur); cur = fmaxf(s2, cur); s2 = lo;
    }

    V[rl][sidx*3+0] = s0; V[rl][sidx*3+1] = s1; V[rl][sidx*3+2] = s2;
    __syncthreads();

    int cl0 = 0, cq0 = 0, cl1 = 0, cq1 = 0, cl2 = 0, cq2 = 0;
    for (int k = 0; k < 48; ++k) {
        float v = V[rl][k];
        cl0 += (v < s0); cq0 += (v <= s0);
        cl1 += (v < s1); cq1 += (v <= s1);
        cl2 += (v < s2); cq2 += (v <= s2);
    }
    if (cl0 <= 12 && 12 < cq0) T[i] = s0 + 0.05f;
    else if (cl1 <= 12 && 12 < cq1) T[i] = s1 + 0.05f;
    else if (cl2 <= 12 && 12 < cq2) T[i] = s2 + 0.05f;
}

// ---------------------------------------------------------------- fused MFMA scan + select + eig + dot
__global__ void tsa_kernel(const unsigned short* __restrict__ rawh,
                           const unsigned short* __restrict__ rawl,
                           const float4* __restrict__ latv,
                           const float4* __restrict__ rawv,
                           const float* __restrict__ sq,
                           const float* __restrict__ T,
                           float* __restrict__ accum) {
    __shared__ unsigned keyS[16 * CAP];   // 24 KB; aliased as ZS/XS in phase 2b
    __shared__ int      cntS[16];
    __shared__ int      nbrAll[16][K_NBR];
    __shared__ int      gotS[16];

    int tid  = threadIdx.x;
    int wave = tid >> 6;
    int lane = tid & 63;
    int quad = lane >> 4;
    int lnib = lane & 15;
    int i0   = blockIdx.x * 16;
    int koff = (quad & 1) * 8;

    if (tid < 16) cntS[tid] = 0;

    // A-frag: 16x16x32 layout A[m=lane&15][k=quad*8+jj]; k<16 = ah, k>=16 = al
    const unsigned short* abase = (quad < 2 ? rawh : rawl) + (size_t)(i0 + lnib) * 16 + koff;
    bf16x8 afrag = *(const bf16x8*)abase;

    float sqi[4], hcut[4];
    #pragma unroll
    for (int r = 0; r < 4; ++r) {
        int m = quad * 4 + r;
        sqi[r]  = sq[i0 + m];
        hcut[r] = 0.5f * (sqi[r] - T[i0 + m]);   // cond: acc > 0.5*sqj + hcut  <=>  d2 < T
    }

    __syncthreads();

    // ---- phase 1: MFMA distance scan, 2 tiles per iteration for ILP
    for (int t = wave; t < B_N / 16; t += 8) {
        int tB = t + 4;
        int jA = t  * 16 + lnib;
        int jB = tB * 16 + lnib;
        bf16x8 bhA = *(const bf16x8*)(rawh + (size_t)jA * 16 + koff);
        bf16x8 blA = *(const bf16x8*)(rawl + (size_t)jA * 16 + koff);
        bf16x8 bhB = *(const bf16x8*)(rawh + (size_t)jB * 16 + koff);
        bf16x8 blB = *(const bf16x8*)(rawl + (size_t)jB * 16 + koff);
        float sqjA = sq[jA];
        float sqjB = sq[jB];
        f32x4 accA = {0.f, 0.f, 0.f, 0.f};
        f32x4 accB = {0.f, 0.f, 0.f, 0.f};
        accA = __builtin_amdgcn_mfma_f32_16x16x32_bf16(afrag, blA, accA, 0, 0, 0);
        accB = __builtin_amdgcn_mfma_f32_16x16x32_bf16(afrag, blB, accB, 0, 0, 0);
        accA = __builtin_amdgcn_mfma_f32_16x16x32_bf16(afrag, bhA, accA, 0, 0, 0);
        accB = __builtin_amdgcn_mfma_f32_16x16x32_bf16(afrag, bhB, accB, 0, 0, 0);
        // C/D layout: col=lane&15 (j), row=quad*4+reg (i)
        #pragma unroll
        for (int r = 0; r < 4; ++r) {
            int m = quad * 4 + r;
            if ((accA[r] > fmaf(0.5f, sqjA, hcut[r])) && (jA != i0 + m)) {
                float d2 = sqi[r] + sqjA - 2.0f * accA[r];
                int pos = atomicAdd(&cntS[m], 1);
                if (pos < CAP) keyS[m * CAP + pos] = (map_f32(d2) & 0xFFFF0000u) | (unsigned)jA;
            }
        }
        #pragma unroll
        for (int r = 0; r < 4; ++r) {
            int m = quad * 4 + r;
            if ((accB[r] > fmaf(0.5f, sqjB, hcut[r])) && (jB != i0 + m)) {
                float d2 = sqi[r] + sqjB - 2.0f * accB[r];
                int pos = atomicAdd(&cntS[m], 1);
                if (pos < CAP) keyS[m * CAP + pos] = (map_f32(d2) & 0xFFFF0000u) | (unsigned)jB;
            }
        }
    }
    __syncthreads();

    // ---- phase 2a: per wave, 4 bisections + ballot-prefix collect (no atomics, no barriers)
    unsigned long long ltm = (1ull << lane) - 1ull;
    for (int rr = 0; rr < 4; ++rr) {
        int m = wave * 4 + rr;
        int C = cntS[m]; C = C < CAP ? C : CAP;
        unsigned kl[MAXL];
        #pragma unroll
        for (int tt = 0; tt < MAXL; ++tt) {
            int c = tt * 64 + lane;
            kl[tt] = (c < C) ? keyS[m * CAP + c] : 0xFFFFFFFFu;
        }
        unsigned lo = 0, hi = 0xFFFFFFFEu;
        for (int it = 0; it < 32 && lo < hi; ++it) {
            unsigned mid = lo + ((hi - lo) >> 1);
            unsigned cc = 0;
            #pragma unroll
            for (int tt = 0; tt < MAXL; ++tt)
                cc += (unsigned)__builtin_popcountll(__ballot(kl[tt] <= mid));
            if (cc >= K_NBR) hi = mid; else lo = mid + 1;
        }
        unsigned T25 = hi;

        int base = 0;
        #pragma unroll
        for (int tt = 0; tt < MAXL; ++tt) {
            bool c = kl[tt] <= T25;
            unsigned long long mk = __ballot(c);
            if (c) {
                int pos = base + __builtin_popcountll(mk & ltm);
                if (pos < K_NBR) nbrAll[m][pos] = (int)(kl[tt] & 0xFFFFu);
            }
            base += __builtin_popcountll(mk);
        }
        if (lane == 0) gotS[m] = base < K_NBR ? base : K_NBR;
    }
    __syncthreads();   // all keyS reads done -> safe to alias

    // ---- phase 2b: eig per wave (ZS/XS carved out of keyS region)
    float* ZS = (float*)keyS + wave * 800;   // 400 floats Z + 400 floats X
    float* XS = ZS + 400;

    for (int rr = 0; rr < 4; ++rr) {
        int m  = wave * 4 + rr;
        int pt = i0 + m;

        if (lane < K_NBR) {
            int got = gotS[m];
            int n = (lane < got) ? nbrAll[m][lane] : ((got > 0) ? nbrAll[m][0] : pt);
            float4* z = (float4*)&ZS[lane * D_DIM];
            float4* x = (float4*)&XS[lane * D_DIM];
            z[0] = latv[n*4+0]; z[1] = latv[n*4+1]; z[2] = latv[n*4+2]; z[3] = latv[n*4+3];
            x[0] = rawv[n*4+0]; x[1] = rawv[n*4+1]; x[2] = rawv[n*4+2]; x[3] = rawv[n*4+3];
        }
        __syncthreads();

        // 4 groups of 16 lanes: (Z,X) x (half0, half1)
        int a     = lane & 15;
        int com   = lane & 16;
        int hb    = lane >> 5;
        int sbase = lane & 48;
        float* M = com ? XS : ZS;

        int k0 = hb ? 13 : 0;
        int k1 = hb ? 25 : 13;
        {
            float s = 0.0f;
            for (int k = k0; k < k1; ++k) s += M[k * D_DIM + a];
            s += __shfl_xor(s, 32, 64);
            float mean = s * 0.04f;
            for (int k = k0; k < k1; ++k) M[k * D_DIM + a] -= mean;
        }
        __syncthreads();

        float row[16];
        #pragma unroll
        for (int b = 0; b < 16; ++b) row[b] = 0.0f;
        for (int k = k0; k < k1; ++k) {
            float va = M[k * D_DIM + a];
            #pragma unroll
            for (int b = 0; b < 16; ++b) row[b] = fmaf(va, M[k * D_DIM + b], row[b]);
        }
        #pragma unroll
        for (int b = 0; b < 16; ++b) row[b] += __shfl_xor(row[b], 32, 64);

        float mm = 1e-30f;
        #pragma unroll
        for (int b = 0; b < 16; ++b) mm = fmaxf(mm, fabsf(row[b]));
        #pragma unroll
        for (int off = 1; off < 16; off <<= 1) mm = fmaxf(mm, __shfl_xor(mm, off, 64));
        float inv = 1.0f / mm;
        #pragma unroll
        for (int b = 0; b < 16; ++b) row[b] *= inv;

        int bbase = sbase + (hb << 3);

        for (int sq3 = 0; sq3 < 3; ++sq3) {   // net C^8
            float rh[8];
            #pragma unroll
            for (int bi = 0; bi < 8; ++bi) rh[bi] = hb ? row[8 + bi] : row[bi];
            float nr[16];
            #pragma unroll
            for (int c = 0; c < 16; ++c) nr[c] = 0.0f;
            #pragma unroll
            for (int bi = 0; bi < 8; ++bi) {
                float coef = rh[bi];
                #pragma unroll
                for (int c = 0; c < 16; ++c)
                    nr[c] = fmaf(coef, __shfl(row[c], bbase + bi, 64), nr[c]);
            }
            #pragma unroll
            for (int c = 0; c < 16; ++c) nr[c] += __shfl_xor(nr[c], 32, 64);
            mm = 1e-30f;
            #pragma unroll
            for (int c = 0; c < 16; ++c) mm = fmaxf(mm, fabsf(nr[c]));
            #pragma unroll
            for (int off = 1; off < 16; off <<= 1) mm = fmaxf(mm, __shfl_xor(mm, off, 64));
            inv = 1.0f / mm;
            #pragma unroll
            for (int c = 0; c < 16; ++c) row[c] = nr[c] * inv;
        }

        float rh[8];
        #pragma unroll
        for (int bi = 0; bi < 8; ++bi) rh[bi] = hb ? row[8 + bi] : row[bi];
        float v = 1.0f + 0.0625f * (float)a;
        for (int it = 0; it < 16; ++it) {     // ~C^128 effective
            float w = 0.0f;
            #pragma unroll
            for (int bi = 0; bi < 8; ++bi)
                w = fmaf(rh[bi], __shfl(v, bbase + bi, 64), w);
            w += __shfl_xor(w, 32, 64);
            float n2 = w * w;
            #pragma unroll
            for (int off = 1; off < 16; off <<= 1) n2 += __shfl_xor(n2, off, 64);
            v = w * rsqrtf(n2 + 1e-37f);
        }
        {
            float n2 = v * v;
            #pragma unroll
            for (int off = 1; off < 16; off <<= 1) n2 += __shfl_xor(n2, off, 64);
            v = v / sqrtf(n2 + 1e-37f);
        }

        float p = v * __shfl_xor(v, 16, 64);
        #pragma unroll
        for (int off = 1; off < 16; off <<= 1) p += __shfl_xor(p, off, 64);
        if (lane == 0) atomicAdd(&accum[1], p * p);
        __syncthreads();
    }
}

// ---------------------------------------------------------------- combine
__global__ void final_kernel(const float* __restrict__ accum, float* __restrict__ out) {
    float recon = accum[0] * (1.0f / (float)(B_N * D_DIM));
    float tsa   = 2.0f - 2.0f * (accum[1] * (1.0f / (float)B_N));
    out[0] = recon + 0.1f * tsa;
}

extern "C" void kernel_launch(void* const* d_in, const int* in_sizes, int n_in,
                              void* d_out, int out_size, void* d_ws, size_t ws_size,
                              hipStream_t stream) {
    const float* outputs = (const float*)d_in[0];
    const float* targets = (const float*)d_in[1];
    const float* latent  = (const float*)d_in[2];
    const float* raw     = (const float*)d_in[3];

    float* accum         = (float*)d_ws;
    float* sq            = (float*)((char*)d_ws + WS_SQ_OFF);
    float* T             = (float*)((char*)d_ws + WS_T_OFF);
    unsigned short* rawh = (unsigned short*)((char*)d_ws + WS_RAWH_OFF);
    unsigned short* rawl = (unsigned short*)((char*)d_ws + WS_RAWL_OFF);

    const float4* rawv = (const float4*)raw;
    const float4* latv = (const float4*)latent;

    hipMemsetAsync(d_ws, 0, 256, stream);  // zero accum
    prep_kernel<<<B_N / 256, 256, 0, stream>>>(rawv, (const float4*)outputs,
                                               (const float4*)targets, sq, rawh, rawl, accum);
    thresh_kernel<<<B_N / 16, 256, 0, stream>>>(rawv, rawh, sq, T);
    tsa_kernel<<<B_N / 16, 256, 0, stream>>>(rawh, rawl, latv, rawv, sq, T, accum);
    final_kernel<<<1, 1, 0, stream>>>(accum, (float*)d_out);
}

// Round 8
// 472.389 us; speedup vs baseline: 2.5369x; 1.0074x over previous
//
#include <hip/hip_runtime.h>
#include <cstdint>
#include <cstddef>

// Problem constants
#define B_N   16384
#define D_DIM 16
#define K_NBR 25
#define CAP   384       // per-row LDS candidate capacity (E[C]~208, sigma~57)
#define MAXL  6         // CAP/64
#define NSAMP 1024      // threshold sample count per row

// Workspace: accum 256B | sq 64KB | T 64KB | rawh 512KB | rawl 512KB
#define WS_SQ_OFF   256
#define WS_T_OFF    (WS_SQ_OFF + 65536)
#define WS_RAWH_OFF (WS_T_OFF + 65536)
#define WS_RAWL_OFF (WS_RAWH_OFF + B_N * D_DIM * 2)

typedef __attribute__((ext_vector_type(8))) short bf16x8;
typedef __attribute__((ext_vector_type(4))) float f32x4;

__device__ __forceinline__ unsigned map_f32(float x) {
    unsigned u = __float_as_uint(x);
    return (u & 0x80000000u) ? ~u : (u | 0x80000000u); // order-preserving
}

__device__ __forceinline__ unsigned short f2bf(float x) {   // RNE f32->bf16 bits
    unsigned u = __float_as_uint(x);
    unsigned r = (u + 0x7FFFu + ((u >> 16) & 1u)) >> 16;
    return (unsigned short)r;
}
__device__ __forceinline__ float bf2f(unsigned short h) {
    return __uint_as_float(((unsigned)h) << 16);
}

// ---------------------------------------------------------------- prep: sq + recon MSE + bf16 hi/lo split
__global__ __launch_bounds__(256) void prep_kernel(const float4* __restrict__ rawv,
                                                   const float4* __restrict__ ov,
                                                   const float4* __restrict__ tv,
                                                   float* __restrict__ sq,
                                                   unsigned short* __restrict__ rawh,
                                                   unsigned short* __restrict__ rawl,
                                                   float* __restrict__ accum) {
    int i = blockIdx.x * 256 + threadIdx.x;
    float v[16];
    {
        float4 r0 = rawv[i*4+0], r1 = rawv[i*4+1], r2 = rawv[i*4+2], r3 = rawv[i*4+3];
        v[0]=r0.x; v[1]=r0.y; v[2]=r0.z; v[3]=r0.w;
        v[4]=r1.x; v[5]=r1.y; v[6]=r1.z; v[7]=r1.w;
        v[8]=r2.x; v[9]=r2.y; v[10]=r2.z; v[11]=r2.w;
        v[12]=r3.x; v[13]=r3.y; v[14]=r3.z; v[15]=r3.w;
    }
    float s = 0.0f;
    unsigned short h[16], l[16];
    #pragma unroll
    for (int k = 0; k < 16; ++k) {
        s = fmaf(v[k], v[k], s);
        unsigned short hh = f2bf(v[k]);
        h[k] = hh;
        l[k] = f2bf(v[k] - bf2f(hh));
    }
    sq[i] = s;
    #pragma unroll
    for (int q = 0; q < 4; ++q) {
        ((ushort4*)(rawh + (size_t)i*16))[q] = make_ushort4(h[q*4], h[q*4+1], h[q*4+2], h[q*4+3]);
        ((ushort4*)(rawl + (size_t)i*16))[q] = make_ushort4(l[q*4], l[q*4+1], l[q*4+2], l[q*4+3]);
    }

    float rs = 0.0f;
    #pragma unroll
    for (int q = 0; q < 4; ++q) {
        float4 o = ov[i*4+q], t = tv[i*4+q];
        float d;
        d = o.x - t.x; rs = fmaf(d, d, rs);
        d = o.y - t.y; rs = fmaf(d, d, rs);
        d = o.z - t.z; rs = fmaf(d, d, rs);
        d = o.w - t.w; rs = fmaf(d, d, rs);
    }
    #pragma unroll
    for (int off = 32; off >= 1; off >>= 1) rs += __shfl_down(rs, off, 64);
    if ((threadIdx.x & 63) == 0) atomicAdd(&accum[0], rs);
}

// ---------------------------------------------------------------- per-row distance threshold, LDS-staged
__global__ __launch_bounds__(256) void thresh_kernel(const float4* __restrict__ rawv,
                                                     const unsigned short* __restrict__ rawh,
                                                     const float* __restrict__ sq,
                                                     float* __restrict__ T) {
    __shared__ unsigned short sampH[NSAMP * 16];  // 32 KB
    __shared__ float sampSq[NSAMP];               // 4 KB
    __shared__ float V[16][48];                   // 3 KB

    int tid = threadIdx.x;
    for (int s = tid; s < NSAMP; s += 256) {
        int js = s << 4;
        const uint4* src = (const uint4*)(rawh + (size_t)js * 16);
        ((uint4*)(sampH + s * 16))[0] = src[0];
        ((uint4*)(sampH + s * 16))[1] = src[1];
        sampSq[s] = sq[js];
    }

    int rl   = tid >> 4;
    int sidx = tid & 15;
    int i = blockIdx.x * 16 + rl;

    float a[16];
    {
        float4 r0 = rawv[i*4+0], r1 = rawv[i*4+1], r2 = rawv[i*4+2], r3 = rawv[i*4+3];
        a[0]=r0.x; a[1]=r0.y; a[2]=r0.z; a[3]=r0.w;
        a[4]=r1.x; a[5]=r1.y; a[6]=r1.z; a[7]=r1.w;
        a[8]=r2.x; a[9]=r2.y; a[10]=r2.z; a[11]=r2.w;
        a[12]=r3.x; a[13]=r3.y; a[14]=r3.z; a[15]=r3.w;
    }
    float sqi = sq[i];
    __syncthreads();

    float s0 = 3e37f, s1 = 3e37f, s2 = 3e37f;
    for (int t = 0; t < NSAMP / 16; ++t) {
        int s = t * 16 + sidx;      // interleaved: consecutive lanes -> consecutive rows
        const uint4* bp = (const uint4*)(sampH + s * 16);
        uint4 h0 = bp[0], h1 = bp[1];
        float dot = 0.0f;
        unsigned w;
        w = h0.x; dot = fmaf(a[0],  __uint_as_float(w << 16), dot); dot = fmaf(a[1],  __uint_as_float(w & 0xFFFF0000u), dot);
        w = h0.y; dot = fmaf(a[2],  __uint_as_float(w << 16), dot); dot = fmaf(a[3],  __uint_as_float(w & 0xFFFF0000u), dot);
        w = h0.z; dot = fmaf(a[4],  __uint_as_float(w << 16), dot); dot = fmaf(a[5],  __uint_as_float(w & 0xFFFF0000u), dot);
        w = h0.w; dot = fmaf(a[6],  __uint_as_float(w << 16), dot); dot = fmaf(a[7],  __uint_as_float(w & 0xFFFF0000u), dot);
        w = h1.x; dot = fmaf(a[8],  __uint_as_float(w << 16), dot); dot = fmaf(a[9],  __uint_as_float(w & 0xFFFF0000u), dot);
        w = h1.y; dot = fmaf(a[10], __uint_as_float(w << 16), dot); dot = fmaf(a[11], __uint_as_float(w & 0xFFFF0000u), dot);
        w = h1.z; dot = fmaf(a[12], __uint_as_float(w << 16), dot); dot = fmaf(a[13], __uint_as_float(w & 0xFFFF0000u), dot);
        w = h1.w; dot = fmaf(a[14], __uint_as_float(w << 16), dot); dot = fmaf(a[15], __uint_as_float(w & 0xFFFF0000u), dot);
        float cur = sqi + sampSq[s] - 2.0f * dot;
        float lo;
        lo = fminf(s0, cur); cur = fmaxf(s0, cur); s0 = lo;
        lo = fminf(s1, cur); cur = fmaxf(s1, cur); s1 = lo;
        lo = fminf(s2, cur); cur = fmaxf(s2, cur); s2 = lo;
    }

    V[rl][sidx*3+0] = s0; V[rl][sidx*3+1] = s1; V[rl][sidx*3+2] = s2;
    __syncthreads();

    int cl0 = 0, cq0 = 0, cl1 = 0, cq1 = 0, cl2 = 0, cq2 = 0;
    for (int k = 0; k < 48; ++k) {
        float v = V[rl][k];
        cl0 += (v < s0); cq0 += (v <= s0);
        cl1 += (v < s1); cq1 += (v <= s1);
        cl2 += (v < s2); cq2 += (v <= s2);
    }
    if (cl0 <= 12 && 12 < cq0) T[i] = s0 + 0.05f;
    else if (cl1 <= 12 && 12 < cq1) T[i] = s1 + 0.05f;
    else if (cl2 <= 12 && 12 < cq2) T[i] = s2 + 0.05f;
}

// ---------------------------------------------------------------- fused MFMA scan + select + eig + dot
__global__ __launch_bounds__(256, 4) void tsa_kernel(const unsigned short* __restrict__ rawh,
                                                     const unsigned short* __restrict__ rawl,
                                                     const float4* __restrict__ latv,
                                                     const float4* __restrict__ rawv,
                                                     const float* __restrict__ sq,
                                                     const float* __restrict__ T,
                                                     float* __restrict__ accum) {
    __shared__ unsigned keyS[16 * CAP];   // 24 KB; aliased as ZS/XS in phase 2b
    __shared__ int      cntS[16];
    __shared__ int      nbrAll[16][K_NBR];
    __shared__ int      gotS[16];

    int tid  = threadIdx.x;
    int wave = tid >> 6;
    int lane = tid & 63;
    int quad = lane >> 4;
    int lnib = lane & 15;
    int i0   = blockIdx.x * 16;
    int koff = (quad & 1) * 8;

    if (tid < 16) cntS[tid] = 0;

    // A-frag: 16x16x32 layout A[m=lane&15][k=quad*8+jj]; k<16 = ah, k>=16 = al
    const unsigned short* abase = (quad < 2 ? rawh : rawl) + (size_t)(i0 + lnib) * 16 + koff;
    bf16x8 afrag = *(const bf16x8*)abase;

    float sqi[4], hcut[4];
    #pragma unroll
    for (int r = 0; r < 4; ++r) {
        int m = quad * 4 + r;
        sqi[r]  = sq[i0 + m];
        hcut[r] = 0.5f * (sqi[r] - T[i0 + m]);   // cond: acc > 0.5*sqj + hcut  <=>  d2 < T
    }

    __syncthreads();

    // ---- phase 1: MFMA distance scan, 2 tiles per iteration for ILP
    for (int t = wave; t < B_N / 16; t += 8) {
        int tB = t + 4;
        int jA = t  * 16 + lnib;
        int jB = tB * 16 + lnib;
        bf16x8 bhA = *(const bf16x8*)(rawh + (size_t)jA * 16 + koff);
        bf16x8 blA = *(const bf16x8*)(rawl + (size_t)jA * 16 + koff);
        bf16x8 bhB = *(const bf16x8*)(rawh + (size_t)jB * 16 + koff);
        bf16x8 blB = *(const bf16x8*)(rawl + (size_t)jB * 16 + koff);
        float sqjA = sq[jA];
        float sqjB = sq[jB];
        f32x4 accA = {0.f, 0.f, 0.f, 0.f};
        f32x4 accB = {0.f, 0.f, 0.f, 0.f};
        accA = __builtin_amdgcn_mfma_f32_16x16x32_bf16(afrag, blA, accA, 0, 0, 0);
        accB = __builtin_amdgcn_mfma_f32_16x16x32_bf16(afrag, blB, accB, 0, 0, 0);
        accA = __builtin_amdgcn_mfma_f32_16x16x32_bf16(afrag, bhA, accA, 0, 0, 0);
        accB = __builtin_amdgcn_mfma_f32_16x16x32_bf16(afrag, bhB, accB, 0, 0, 0);
        // C/D layout: col=lane&15 (j), row=quad*4+reg (i)
        #pragma unroll
        for (int r = 0; r < 4; ++r) {
            int m = quad * 4 + r;
            if ((accA[r] > fmaf(0.5f, sqjA, hcut[r])) && (jA != i0 + m)) {
                float d2 = sqi[r] + sqjA - 2.0f * accA[r];
                int pos = atomicAdd(&cntS[m], 1);
                if (pos < CAP) keyS[m * CAP + pos] = (map_f32(d2) & 0xFFFF0000u) | (unsigned)jA;
            }
        }
        #pragma unroll
        for (int r = 0; r < 4; ++r) {
            int m = quad * 4 + r;
            if ((accB[r] > fmaf(0.5f, sqjB, hcut[r])) && (jB != i0 + m)) {
                float d2 = sqi[r] + sqjB - 2.0f * accB[r];
                int pos = atomicAdd(&cntS[m], 1);
                if (pos < CAP) keyS[m * CAP + pos] = (map_f32(d2) & 0xFFFF0000u) | (unsigned)jB;
            }
        }
    }
    __syncthreads();

    // ---- phase 2a: per wave, 4 bisections + ballot-prefix collect (no atomics, no barriers)
    unsigned long long ltm = (1ull << lane) - 1ull;
    for (int rr = 0; rr < 4; ++rr) {
        int m = wave * 4 + rr;
        int C = cntS[m]; C = C < CAP ? C : CAP;
        unsigned kl[MAXL];
        #pragma unroll
        for (int tt = 0; tt < MAXL; ++tt) {
            int c = tt * 64 + lane;
            kl[tt] = (c < C) ? keyS[m * CAP + c] : 0xFFFFFFFFu;
        }
        unsigned lo = 0, hi = 0xFFFFFFFEu;
        for (int it = 0; it < 32 && lo < hi; ++it) {
            unsigned mid = lo + ((hi - lo) >> 1);
            unsigned cc = 0;
            #pragma unroll
            for (int tt = 0; tt < MAXL; ++tt)
                cc += (unsigned)__builtin_popcountll(__ballot(kl[tt] <= mid));
            if (cc >= K_NBR) hi = mid; else lo = mid + 1;
        }
        unsigned T25 = hi;

        int base = 0;
        #pragma unroll
        for (int tt = 0; tt < MAXL; ++tt) {
            bool c = kl[tt] <= T25;
            unsigned long long mk = __ballot(c);
            if (c) {
                int pos = base + __builtin_popcountll(mk & ltm);
                if (pos < K_NBR) nbrAll[m][pos] = (int)(kl[tt] & 0xFFFFu);
            }
            base += __builtin_popcountll(mk);
        }
        if (lane == 0) gotS[m] = base < K_NBR ? base : K_NBR;
    }
    __syncthreads();   // all keyS reads done -> safe to alias

    // ---- phase 2b: eig per wave (ZS/XS carved out of keyS region)
    float* ZS = (float*)keyS + wave * 800;   // 400 floats Z + 400 floats X
    float* XS = ZS + 400;

    for (int rr = 0; rr < 4; ++rr) {
        int m  = wave * 4 + rr;
        int pt = i0 + m;

        if (lane < K_NBR) {
            int got = gotS[m];
            int n = (lane < got) ? nbrAll[m][lane] : ((got > 0) ? nbrAll[m][0] : pt);
            float4* z = (float4*)&ZS[lane * D_DIM];
            float4* x = (float4*)&XS[lane * D_DIM];
            z[0] = latv[n*4+0]; z[1] = latv[n*4+1]; z[2] = latv[n*4+2]; z[3] = latv[n*4+3];
            x[0] = rawv[n*4+0]; x[1] = rawv[n*4+1]; x[2] = rawv[n*4+2]; x[3] = rawv[n*4+3];
        }
        __syncthreads();

        // 4 groups of 16 lanes: (Z,X) x (half0, half1)
        int a     = lane & 15;
        int com   = lane & 16;
        int hb    = lane >> 5;
        int sbase = lane & 48;
        float* M = com ? XS : ZS;

        int k0 = hb ? 13 : 0;
        int k1 = hb ? 25 : 13;
        {
            float s = 0.0f;
            for (int k = k0; k < k1; ++k) s += M[k * D_DIM + a];
            s += __shfl_xor(s, 32, 64);
            float mean = s * 0.04f;
            for (int k = k0; k < k1; ++k) M[k * D_DIM + a] -= mean;
        }
        __syncthreads();

        float row[16];
        #pragma unroll
        for (int b = 0; b < 16; ++b) row[b] = 0.0f;
        for (int k = k0; k < k1; ++k) {
            float va = M[k * D_DIM + a];
            #pragma unroll
            for (int b = 0; b < 16; ++b) row[b] = fmaf(va, M[k * D_DIM + b], row[b]);
        }
        #pragma unroll
        for (int b = 0; b < 16; ++b) row[b] += __shfl_xor(row[b], 32, 64);

        float mm = 1e-30f;
        #pragma unroll
        for (int b = 0; b < 16; ++b) mm = fmaxf(mm, fabsf(row[b]));
        #pragma unroll
        for (int off = 1; off < 16; off <<= 1) mm = fmaxf(mm, __shfl_xor(mm, off, 64));
        float inv = 1.0f / mm;
        #pragma unroll
        for (int b = 0; b < 16; ++b) row[b] *= inv;

        int bbase = sbase + (hb << 3);

        for (int sq3 = 0; sq3 < 3; ++sq3) {   // net C^8
            float rh[8];
            #pragma unroll
            for (int bi = 0; bi < 8; ++bi) rh[bi] = hb ? row[8 + bi] : row[bi];
            float nr[16];
            #pragma unroll
            for (int c = 0; c < 16; ++c) nr[c] = 0.0f;
            #pragma unroll
            for (int bi = 0; bi < 8; ++bi) {
                float coef = rh[bi];
                #pragma unroll
                for (int c = 0; c < 16; ++c)
                    nr[c] = fmaf(coef, __shfl(row[c], bbase + bi, 64), nr[c]);
            }
            #pragma unroll
            for (int c = 0; c < 16; ++c) nr[c] += __shfl_xor(nr[c], 32, 64);
            mm = 1e-30f;
            #pragma unroll
            for (int c = 0; c < 16; ++c) mm = fmaxf(mm, fabsf(nr[c]));
            #pragma unroll
            for (int off = 1; off < 16; off <<= 1) mm = fmaxf(mm, __shfl_xor(mm, off, 64));
            inv = 1.0f / mm;
            #pragma unroll
            for (int c = 0; c < 16; ++c) row[c] = nr[c] * inv;
        }

        float rh[8];
        #pragma unroll
        for (int bi = 0; bi < 8; ++bi) rh[bi] = hb ? row[8 + bi] : row[bi];
        float v = 1.0f + 0.0625f * (float)a;
        for (int it = 0; it < 16; ++it) {     // ~C^128 effective
            float w = 0.0f;
            #pragma unroll
            for (int bi = 0; bi < 8; ++bi)
                w = fmaf(rh[bi], __shfl(v, bbase + bi, 64), w);
            w += __shfl_xor(w, 32, 64);
            float n2 = w * w;
            #pragma unroll
            for (int off = 1; off < 16; off <<= 1) n2 += __shfl_xor(n2, off, 64);
            v = w * rsqrtf(n2 + 1e-37f);
        }
        {
            float n2 = v * v;
            #pragma unroll
            for (int off = 1; off < 16; off <<= 1) n2 += __shfl_xor(n2, off, 64);
            v = v / sqrtf(n2 + 1e-37f);
        }

        float p = v * __shfl_xor(v, 16, 64);
        #pragma unroll
        for (int off = 1; off < 16; off <<= 1) p += __shfl_xor(p, off, 64);
        if (lane == 0) atomicAdd(&accum[1], p * p);
        __syncthreads();
    }
}

// ---------------------------------------------------------------- combine
__global__ void final_kernel(const float* __restrict__ accum, float* __restrict__ out) {
    float recon = accum[0] * (1.0f / (float)(B_N * D_DIM));
    float tsa   = 2.0f - 2.0f * (accum[1] * (1.0f / (float)B_N));
    out[0] = recon + 0.1f * tsa;
}

extern "C" void kernel_launch(void* const* d_in, const int* in_sizes, int n_in,
                              void* d_out, int out_size, void* d_ws, size_t ws_size,
                              hipStream_t stream) {
    const float* outputs = (const float*)d_in[0];
    const float* targets = (const float*)d_in[1];
    const float* latent  = (const float*)d_in[2];
    const float* raw     = (const float*)d_in[3];

    float* accum         = (float*)d_ws;
    float* sq            = (float*)((char*)d_ws + WS_SQ_OFF);
    float* T             = (float*)((char*)d_ws + WS_T_OFF);
    unsigned short* rawh = (unsigned short*)((char*)d_ws + WS_RAWH_OFF);
    unsigned short* rawl = (unsigned short*)((char*)d_ws + WS_RAWL_OFF);

    const float4* rawv = (const float4*)raw;
    const float4* latv = (const float4*)latent;

    hipMemsetAsync(d_ws, 0, 256, stream);  // zero accum
    prep_kernel<<<B_N / 256, 256, 0, stream>>>(rawv, (const float4*)outputs,
                                               (const float4*)targets, sq, rawh, rawl, accum);
    thresh_kernel<<<B_N / 16, 256, 0, stream>>>(rawv, rawh, sq, T);
    tsa_kernel<<<B_N / 16, 256, 0, stream>>>(rawh, rawl, latv, rawv, sq, T, accum);
    final_kernel<<<1, 1, 0, stream>>>(accum, (float*)d_out);
}